// Round 14
// baseline (572.227 us; speedup 1.0000x reference)
//
#include <hip/hip_runtime.h>
#include <math.h>

#define TPB 256

// ---------------------------------------------------------------------------
// Geometry:
//   x: [8, 1, 128, 1024] f32
//   L0: CI=1,  CO=16, 128x1024, pool -> 64x512   (fused offsets)
//   L1: CI=16, CO=32, 64x512,   pool -> 32x256   dfc_og OGC=1
//   L2: CI=32, CO=48, 32x256,   pool -> 16x128   dfc_og OGC=2
//   L3: CI=48, CO=64, 16x128,   no pool          dfc_wave8 (R14)
//   L4: CI=64, CO=80, 16x128,   no pool -> d_out dfc_wave8 (R14)
//
// R13 lesson: slds' OGB duplication cancelled its coalescing win (TA /6 * 4),
// and ROWD pad was wrong (stride mod 32: 12 vs 4 — same gcd, same conflicts).
// R14 dfc_wave8: P=64 px/block, TPB=512, og = WAVE id -> 8 og-groups share
// ONE gather (no duplication), og wave-uniform -> weights stay s_load.
// LDS XOR swizzle u = p ^ (s&7): write = 8 accesses/bank-group (minimum),
// read = permuted contiguous 1KB row. Both conflict-free.
// R9 lesson: no register pipeline arrays (spill cliff).
// Kept: NHWC activations, wave-uniform s_load weights, XCD swizzle,
// no launch_bounds min-wave cap beyond thread count, bounded unrolls.
// ---------------------------------------------------------------------------

// Packed-weight workspace offsets (floats)
#define OWM0 0
#define OWM1 144
#define OWM2 4752
#define OWM3 18576
#define OWM4 46224
#define OWO0 92304
#define OWO1 92484
#define OWO2 95940
#define OWO3 102852
#define OWO4 113220
#define PACK_FLOATS 131072

struct PackSrc { const float* p[10]; };  // 0-4: wmain, 5-9: woff

__global__ void pack_weights(PackSrc s, float* __restrict__ dst) {
  int seg = blockIdx.y;
  int idx = blockIdx.x * TPB + threadIdx.x;
  int CI, CO, ow;
  if (seg < 5) {
    if (seg == 0)      { CI = 1;  CO = 16; ow = OWM0; }
    else if (seg == 1) { CI = 16; CO = 32; ow = OWM1; }
    else if (seg == 2) { CI = 32; CO = 48; ow = OWM2; }
    else if (seg == 3) { CI = 48; CO = 64; ow = OWM3; }
    else               { CI = 64; CO = 80; ow = OWM4; }
    int n = 9 * CI * CO;
    if (idx >= n) return;
    int o = idx % CO, rest = idx / CO;
    int c = rest % CI, k = rest / CI;
    dst[ow + idx] = s.p[seg][((size_t)o * CI + c) * 9 + k];
  } else if (seg == 5) {
    if (idx >= 180) return;
    int j = idx % 20, t = idx / 20;
    dst[OWO0 + idx] = (j < 18) ? s.p[5][j * 9 + t] : 0.f;
  } else {
    if (seg == 6)      { CI = 16; ow = OWO1; }
    else if (seg == 7) { CI = 32; ow = OWO2; }
    else if (seg == 8) { CI = 48; ow = OWO3; }
    else               { CI = 64; ow = OWO4; }
    int n = 3 * CI * 9 * 8;
    if (idx >= n) return;
    int u = idx % 8, r = idx / 8;
    int t = r % 9, c = (r / 9) % CI, jg = r / (9 * CI);
    dst[ow + idx] = (u < 6) ? s.p[seg][((size_t)(jg * 6 + u) * CI + c) * 9 + t] : 0.f;
  }
}

// XCD-aware swizzle: nwg % 8 == 0 at every launch site.
__device__ __forceinline__ int xcd_swz(int bid, int nwg) {
  return (bid & 7) * (nwg >> 3) + (bid >> 3);
}

// ---------------------------------------------------------------------------
// L0: CI=1 (NCHW==NHWC) -> fused offsets + deform conv, out NCHW.
// ---------------------------------------------------------------------------
__global__ __launch_bounds__(TPB) void dfc_fused0(
    const float* __restrict__ x, const float* __restrict__ woP,   // [9][20]
    const float* __restrict__ boff, const float* __restrict__ wmP, // [9][16]
    float* __restrict__ out, int B, int H, int W) {
  const int idx = xcd_swz(blockIdx.x, gridDim.x) * TPB + threadIdx.x;
  const int HW = H * W;
  const int w = idx % W;
  const int h = (idx / W) % H;
  const int b = idx / HW;
  const float* xp = x + (size_t)b * HW;

  float xv[9];
#pragma unroll
  for (int t = 0; t < 9; t++) {
    int yy = h - 1 + t / 3, xx = w - 1 + t % 3;
    xv[t] = (yy >= 0 && yy < H && xx >= 0 && xx < W) ? xp[yy * W + xx] : 0.f;
  }

  float offv[18];
#pragma unroll
  for (int j = 0; j < 18; j++) offv[j] = boff[j];
#pragma unroll
  for (int t = 0; t < 9; t++) {
    const float* wr = &woP[t * 20];
#pragma unroll
    for (int j = 0; j < 18; j++) offv[j] = fmaf(xv[t], wr[j], offv[j]);
  }

  float acc[16];
#pragma unroll
  for (int o = 0; o < 16; o++) acc[o] = 0.f;

#pragma unroll
  for (int k = 0; k < 9; k++) {
    float py = (float)(h - 1 + k / 3) + offv[2 * k];
    float px = (float)(w - 1 + k % 3) + offv[2 * k + 1];
    float fy = floorf(py), fx = floorf(px);
    float wy = py - fy, wx = px - fx;
    int y0 = (int)fy, x0 = (int)fx;
    int y1 = y0 + 1, x1 = x0 + 1;
    bool vy0 = (y0 >= 0) & (y0 < H), vy1 = (y1 >= 0) & (y1 < H);
    bool vx0 = (x0 >= 0) & (x0 < W), vx1 = (x1 >= 0) & (x1 < W);
    int yc0 = min(max(y0, 0), H - 1), yc1 = min(max(y1, 0), H - 1);
    int xc0 = min(max(x0, 0), W - 1), xc1 = min(max(x1, 0), W - 1);
    float w00 = (vy0 && vx0) ? (1.f - wy) * (1.f - wx) : 0.f;
    float w01 = (vy0 && vx1) ? (1.f - wy) * wx : 0.f;
    float w10 = (vy1 && vx0) ? wy * (1.f - wx) : 0.f;
    float w11 = (vy1 && vx1) ? wy * wx : 0.f;
    float sv = xp[yc0 * W + xc0] * w00 + xp[yc0 * W + xc1] * w01
             + xp[yc1 * W + xc0] * w10 + xp[yc1 * W + xc1] * w11;
    const float* wr = &wmP[k * 16];
#pragma unroll
    for (int o = 0; o < 16; o++) acc[o] = fmaf(sv, wr[o], acc[o]);
  }

  float* op = out + (size_t)b * 16 * HW + h * W + w;
#pragma unroll
  for (int o = 0; o < 16; o++) op[(size_t)o * HW] = acc[o];
}

// ---------------------------------------------------------------------------
// Offset conv (L1-L4): x NHWC, per tap CI/4 float4 loads, s_load weights.
// ---------------------------------------------------------------------------
template<int CI, int TPBK>
__global__ __launch_bounds__(TPBK) void off_conv(
    const float* __restrict__ x, const float* __restrict__ wP,
    const float* __restrict__ boff, float* __restrict__ off,
    int B, int H, int W) {
  const int HW = H * W;
  const int npb = HW / TPBK;
  const int bid = xcd_swz(blockIdx.x, gridDim.x);
  const int pxb = bid % npb;
  const int jg = (bid / npb) % 3;
  const int b = bid / (3 * npb);
  const int px = pxb * TPBK + threadIdx.x;
  const int w = px % W, h = px / W;
  const float* xb = x + (size_t)b * HW * CI;
  const float* wj = wP + (size_t)jg * CI * 9 * 8;

  float acc[6];
#pragma unroll
  for (int u = 0; u < 6; u++) acc[u] = boff[jg * 6 + u];

#pragma unroll 1
  for (int t = 0; t < 9; t++) {
    int yy = h - 1 + t / 3, xx = w - 1 + t % 3;
    bool vld = (yy >= 0 && yy < H && xx >= 0 && xx < W);
    int a = vld ? (yy * W + xx) : 0;
    const float* xp = xb + (size_t)a * CI;
    const float* wt = wj + t * 8;
#pragma unroll 4
    for (int cg = 0; cg < CI / 4; cg++) {
      float4 v = *(const float4*)(xp + cg * 4);
      float s0 = vld ? v.x : 0.f;
      float s1 = vld ? v.y : 0.f;
      float s2 = vld ? v.z : 0.f;
      float s3 = vld ? v.w : 0.f;
      const float* w0 = wt + (size_t)cg * 4 * 72;
#pragma unroll
      for (int u = 0; u < 6; u++) {
        float a0 = fmaf(s0, w0[u], acc[u]);
        float a1 = fmaf(s1, w0[72 + u], a0);
        float a2 = fmaf(s2, w0[144 + u], a1);
        acc[u] = fmaf(s3, w0[216 + u], a2);
      }
    }
  }
#pragma unroll
  for (int u = 0; u < 6; u++)
    off[((size_t)b * 18 + jg * 6 + u) * HW + px] = acc[u];
}

// ---------------------------------------------------------------------------
// Deform conv, og-split per-pixel-thread (L1, L2).
// ---------------------------------------------------------------------------
template<int CI, int CO, int OGC, int TPBK>
__global__ __launch_bounds__(TPBK) void dfc_og(
    const float* __restrict__ x, const float* __restrict__ off,
    const float* __restrict__ wP, float* __restrict__ out,
    int B, int H, int W) {
  constexpr int COG = CO / OGC;
  const int HW = H * W;
  const int npb = HW / TPBK;
  const int bid = xcd_swz(blockIdx.x, gridDim.x);
  const int og = bid % OGC;
  const int pxb = (bid / OGC) % npb;
  const int b = bid / (OGC * npb);
  const int px = pxb * TPBK + threadIdx.x;
  const int w = px % W, h = px / W;
  const float* xb = x + (size_t)b * HW * CI;   // NHWC

  float offv[18];
  const float* ob = off + (size_t)b * 18 * HW + px;
#pragma unroll
  for (int j = 0; j < 18; j++) offv[j] = ob[(size_t)j * HW];

  float acc[COG];
#pragma unroll
  for (int o = 0; o < COG; o++) acc[o] = 0.f;

#pragma unroll
  for (int k = 0; k < 9; k++) {
    float py = (float)(h - 1 + k / 3) + offv[2 * k];
    float pxx = (float)(w - 1 + k % 3) + offv[2 * k + 1];
    float fy = floorf(py), fx = floorf(pxx);
    float wy = py - fy, wx = pxx - fx;
    int y0 = (int)fy, x0 = (int)fx;
    int y1 = y0 + 1, x1 = x0 + 1;
    bool vy0 = (y0 >= 0) & (y0 < H), vy1 = (y1 >= 0) & (y1 < H);
    bool vx0 = (x0 >= 0) & (x0 < W), vx1 = (x1 >= 0) & (x1 < W);
    int yc0 = min(max(y0, 0), H - 1), yc1 = min(max(y1, 0), H - 1);
    int xc0 = min(max(x0, 0), W - 1), xc1 = min(max(x1, 0), W - 1);
    float w00 = (vy0 && vx0) ? (1.f - wy) * (1.f - wx) : 0.f;
    float w01 = (vy0 && vx1) ? (1.f - wy) * wx : 0.f;
    float w10 = (vy1 && vx0) ? wy * (1.f - wx) : 0.f;
    float w11 = (vy1 && vx1) ? wy * wx : 0.f;
    const float* p00 = xb + (size_t)(yc0 * W + xc0) * CI;
    const float* p01 = xb + (size_t)(yc0 * W + xc1) * CI;
    const float* p10 = xb + (size_t)(yc1 * W + xc0) * CI;
    const float* p11 = xb + (size_t)(yc1 * W + xc1) * CI;
#pragma unroll 2
    for (int cg = 0; cg < CI / 4; cg++) {
      float4 v00 = *(const float4*)(p00 + cg * 4);
      float4 v01 = *(const float4*)(p01 + cg * 4);
      float4 v10 = *(const float4*)(p10 + cg * 4);
      float4 v11 = *(const float4*)(p11 + cg * 4);
      float s0 = v00.x * w00 + v01.x * w01 + v10.x * w10 + v11.x * w11;
      float s1 = v00.y * w00 + v01.y * w01 + v10.y * w10 + v11.y * w11;
      float s2 = v00.z * w00 + v01.z * w01 + v10.z * w10 + v11.z * w11;
      float s3 = v00.w * w00 + v01.w * w01 + v10.w * w10 + v11.w * w11;
      const float* wr = wP + (size_t)(k * CI + cg * 4) * CO + og * COG;
#pragma unroll
      for (int o = 0; o < COG; o++) {
        float a0 = fmaf(s0, wr[o], acc[o]);
        float a1 = fmaf(s1, wr[CO + o], a0);
        float a2 = fmaf(s2, wr[2 * CO + o], a1);
        acc[o] = fmaf(s3, wr[3 * CO + o], a2);
      }
    }
  }

  float* op = out + ((size_t)b * CO + og * COG) * HW + px;
#pragma unroll
  for (int o = 0; o < COG; o++) op[(size_t)o * HW] = acc[o];
}

// ---------------------------------------------------------------------------
// dfc_wave8 (L3-L4): P=64 pixels/block, TPB=512 (8 waves). Gather phase:
// thread=(pixel,slice), consecutive lanes = consecutive slices (coalesced),
// each (px,slice) gathered ONCE into LDS. Compute phase: lane=pixel,
// og = wave id (wave-uniform -> s_load weights), all 8 og-groups share the
// staged samples. LDS XOR swizzle u = p ^ (s&7): both sides conflict-free.
// ---------------------------------------------------------------------------
template<int CI, int CO>
__global__ __launch_bounds__(512) void dfc_wave8(
    const float* __restrict__ x, const float* __restrict__ off,
    const float* __restrict__ wP, float* __restrict__ out,
    int B, int H, int W) {
  constexpr int P = 64;
  constexpr int S = CI / 4;
  constexpr int COG = CO / 8;
  constexpr int NT = (P * S + 511) / 512;

  __shared__ float s_off[18 * P];
  __shared__ float s_samp[S * P * 4];   // [s][u=p^(s&7)][4dw]

  const int HW = H * W;
  const int npb = HW / P;
  const int bid = xcd_swz(blockIdx.x, gridDim.x);
  const int pxb = bid % npb;
  const int b = bid / npb;
  const int px0 = pxb * P;
  const int tid = threadIdx.x;
  const float* xb = x + (size_t)b * HW * CI;

  for (int t = tid; t < 18 * P; t += 512) {
    int j = t / P, p = t % P;
    s_off[t] = off[((size_t)b * 18 + j) * HW + px0 + p];
  }

  const int lane = tid & 63;
  const int og = tid >> 6;           // wave id: wave-uniform og group

  float acc[COG];
#pragma unroll
  for (int o = 0; o < COG; o++) acc[o] = 0.f;

#pragma unroll 1
  for (int k = 0; k < 9; k++) {
    __syncthreads();   // k=0: s_off ready; k>0: compute done with s_samp
    // ---- gather phase
#pragma unroll
    for (int tt = 0; tt < NT; tt++) {
      int t = tt * 512 + tid;
      if ((P * S) % 512 == 0 || t < P * S) {
        int s = t % S, p = t / S;
        int px = px0 + p;
        int w = px % W, h = px / W;
        float dy = s_off[(2 * k) * P + p];
        float dx = s_off[(2 * k + 1) * P + p];
        float py = (float)(h - 1 + k / 3) + dy;
        float pxx = (float)(w - 1 + k % 3) + dx;
        float fy = floorf(py), fx = floorf(pxx);
        float wy = py - fy, wx = pxx - fx;
        int y0 = (int)fy, x0 = (int)fx;
        int y1 = y0 + 1, x1 = x0 + 1;
        bool vy0 = (y0 >= 0) & (y0 < H), vy1 = (y1 >= 0) & (y1 < H);
        bool vx0 = (x0 >= 0) & (x0 < W), vx1 = (x1 >= 0) & (x1 < W);
        int yc0 = min(max(y0, 0), H - 1), yc1 = min(max(y1, 0), H - 1);
        int xc0 = min(max(x0, 0), W - 1), xc1 = min(max(x1, 0), W - 1);
        float w00 = (vy0 && vx0) ? (1.f - wy) * (1.f - wx) : 0.f;
        float w01 = (vy0 && vx1) ? (1.f - wy) * wx : 0.f;
        float w10 = (vy1 && vx0) ? wy * (1.f - wx) : 0.f;
        float w11 = (vy1 && vx1) ? wy * wx : 0.f;
        float4 v00 = *(const float4*)(xb + (size_t)(yc0 * W + xc0) * CI + s * 4);
        float4 v01 = *(const float4*)(xb + (size_t)(yc0 * W + xc1) * CI + s * 4);
        float4 v10 = *(const float4*)(xb + (size_t)(yc1 * W + xc0) * CI + s * 4);
        float4 v11 = *(const float4*)(xb + (size_t)(yc1 * W + xc1) * CI + s * 4);
        float4 sv;
        sv.x = v00.x * w00 + v01.x * w01 + v10.x * w10 + v11.x * w11;
        sv.y = v00.y * w00 + v01.y * w01 + v10.y * w10 + v11.y * w11;
        sv.z = v00.z * w00 + v01.z * w01 + v10.z * w10 + v11.z * w11;
        sv.w = v00.w * w00 + v01.w * w01 + v10.w * w10 + v11.w * w11;
        int u = p ^ (s & 7);
        *(float4*)&s_samp[(s * P + u) * 4] = sv;
      }
    }
    __syncthreads();
    // ---- compute phase: lane = pixel, og wave-uniform
#pragma unroll
    for (int s = 0; s < S; s++) {
      float4 sv = *(const float4*)&s_samp[(s * P + (lane ^ (s & 7))) * 4];
      const float* wr = wP + (size_t)(k * CI + s * 4) * CO + og * COG;
#pragma unroll
      for (int o = 0; o < COG; o++) {
        float a0 = fmaf(sv.x, wr[o], acc[o]);
        float a1 = fmaf(sv.y, wr[CO + o], a0);
        float a2 = fmaf(sv.z, wr[2 * CO + o], a1);
        acc[o] = fmaf(sv.w, wr[3 * CO + o], a2);
      }
    }
  }

  float* op = out + ((size_t)b * CO + og * COG) * HW + px0 + lane;
#pragma unroll
  for (int o = 0; o < COG; o++) op[(size_t)o * HW] = acc[o];
}

// ---------------------------------------------------------------------------
// BatchNorm (training stats, y NCHW) + LeakyReLU; apply writes NHWC or NCHW.
// ---------------------------------------------------------------------------
__global__ void bn_stats_kernel(const float* __restrict__ y,
                                double* __restrict__ st,
                                int B, int C, int HW, int NB) {
  int c = blockIdx.x / NB;
  int sl = blockIdx.x % NB;
  int tid = threadIdx.x;
  double s = 0.0, s2 = 0.0;
  int HW4 = HW >> 2;
  for (int b = 0; b < B; b++) {
    const float4* p = (const float4*)(y + ((size_t)b * C + c) * HW);
    for (int i = sl * TPB + tid; i < HW4; i += NB * TPB) {
      float4 v = p[i];
      s += (double)v.x + (double)v.y + (double)v.z + (double)v.w;
      s2 += (double)v.x * v.x + (double)v.y * v.y
          + (double)v.z * v.z + (double)v.w * v.w;
    }
  }
  __shared__ double rs[TPB], rq[TPB];
  rs[tid] = s;
  rq[tid] = s2;
  __syncthreads();
  for (int o = TPB / 2; o > 0; o >>= 1) {
    if (tid < o) { rs[tid] += rs[tid + o]; rq[tid] += rq[tid + o]; }
    __syncthreads();
  }
  if (tid == 0) {
    atomicAdd(&st[2 * c], rs[0]);
    atomicAdd(&st[2 * c + 1], rq[0]);
  }
}

__global__ void bn_finalize_kernel(const double* __restrict__ st,
                                   const float* __restrict__ g,
                                   const float* __restrict__ bb,
                                   float* __restrict__ ss, int C, int N) {
  int c = threadIdx.x;
  if (c >= C) return;
  double mean = st[2 * c] / N;
  double var = st[2 * c + 1] / N - mean * mean;
  float inv = (float)(1.0 / sqrt(var + 1e-5));
  float sc = g[c] * inv;
  ss[c] = sc;
  ss[C + c] = bb[c] - (float)mean * sc;
}

// NCHW -> NCHW (final output)
__global__ void bn_apply_kernel(const float* __restrict__ y,
                                const float* __restrict__ ss,
                                float* __restrict__ out, int C, int HW, int n) {
  int i = blockIdx.x * TPB + threadIdx.x;
  if (i >= n) return;
  int c = (i / HW) % C;
  float v = fmaf(y[i], ss[c], ss[C + c]);
  out[i] = v > 0.f ? v : 0.01f * v;
}

// NCHW -> NHWC (no pool; L3)
__global__ void bn_apply_nhwc_kernel(const float* __restrict__ y,
                                     const float* __restrict__ ss,
                                     float* __restrict__ out,
                                     int C, int H, int W, int n) {
  int i = blockIdx.x * TPB + threadIdx.x;
  if (i >= n) return;
  int c = i % C;
  int pix = i / C;
  int w = pix % W;
  int h = (pix / W) % H;
  int b = pix / (W * H);
  float v = fmaf(y[(((size_t)b * C + c) * H + h) * W + w], ss[c], ss[C + c]);
  out[i] = v > 0.f ? v : 0.01f * v;
}

// NCHW -> 2x2 maxpool -> NHWC (L0,L1,L2)
__global__ void bn_apply_pool_nhwc_kernel(const float* __restrict__ y,
                                          const float* __restrict__ ss,
                                          float* __restrict__ out,
                                          int C, int H, int W, int n) {
  int i = blockIdx.x * TPB + threadIdx.x;
  if (i >= n) return;
  int Wp = W >> 1, Hp = H >> 1;
  int c = i % C;
  int pw = (i / C) % Wp;
  int ph = (i / C / Wp) % Hp;
  int b = i / (C * Wp * Hp);
  const float* yp = y + (((size_t)b * C + c) * H + 2 * ph) * W + 2 * pw;
  float sc = ss[c], sh = ss[C + c];
  float v0 = fmaf(yp[0], sc, sh);     v0 = v0 > 0.f ? v0 : 0.01f * v0;
  float v1 = fmaf(yp[1], sc, sh);     v1 = v1 > 0.f ? v1 : 0.01f * v1;
  float v2 = fmaf(yp[W], sc, sh);     v2 = v2 > 0.f ? v2 : 0.01f * v2;
  float v3 = fmaf(yp[W + 1], sc, sh); v3 = v3 > 0.f ? v3 : 0.01f * v3;
  out[i] = fmaxf(fmaxf(v0, v1), fmaxf(v2, v3));
}

extern "C" void kernel_launch(void* const* d_in, const int* in_sizes, int n_in,
                              void* d_out, int out_size, void* d_ws, size_t ws_size,
                              hipStream_t stream) {
  const float* x = (const float*)d_in[0];
  const float *woff[5], *boff[5], *wm[5], *g[5], *bb[5];
  for (int i = 0; i < 5; i++) {
    woff[i] = (const float*)d_in[1 + 5 * i + 0];
    boff[i] = (const float*)d_in[1 + 5 * i + 1];
    wm[i]   = (const float*)d_in[1 + 5 * i + 2];
    g[i]    = (const float*)d_in[1 + 5 * i + 3];
    bb[i]   = (const float*)d_in[1 + 5 * i + 4];
  }

  const size_t need =
      (size_t)(16777216 + 4718592 + 4194304 + 2097152 + PACK_FLOATS) * 4 + 6400 + 640;
  if (ws_size < need) return;

  float* conv_buf = (float*)d_ws;          // NCHW conv outputs (up to 67 MB)
  float* off_buf = conv_buf + 16777216;    // offsets [b][18][HW]
  float* xa = off_buf + 4718592;           // x1 / x3 (NHWC)
  float* xb2 = xa + 4194304;               // x2 / x4 (NHWC)
  float* wpk = xb2 + 2097152;              // packed weights
  double* st = (double*)(wpk + PACK_FLOATS);   // 5 x 160 doubles
  float* ss = (float*)(st + 800);

  const int B = 8;

  {
    PackSrc psrc;
    for (int i = 0; i < 5; i++) { psrc.p[i] = wm[i]; psrc.p[5 + i] = woff[i]; }
    pack_weights<<<dim3(180, 10), TPB, 0, stream>>>(psrc, wpk);
    hipMemsetAsync(st, 0, 800 * sizeof(double), stream);   // all layers' stats
  }

  auto bn_head = [&](const float* ybuf, int C, int H, int W, int NB,
                     const float* gg, const float* bbb, int layer) {
    double* stl = st + 160 * layer;
    bn_stats_kernel<<<C * NB, TPB, 0, stream>>>(ybuf, stl, B, C, H * W, NB);
    bn_finalize_kernel<<<1, TPB, 0, stream>>>(stl, gg, bbb, ss, C, B * H * W);
  };

  // ---- Layer 0: CI=1, CO=16, 128x1024, fused offsets, pool -> xa (NHWC)
  {
    const int H = 128, W = 1024;
    dfc_fused0<<<B * H * W / TPB, TPB, 0, stream>>>(
        x, wpk + OWO0, boff[0], wpk + OWM0, conv_buf, B, H, W);
    bn_head(conv_buf, 16, H, W, 32, g[0], bb[0], 0);
    int n = B * 16 * (H / 2) * (W / 2);
    bn_apply_pool_nhwc_kernel<<<n / TPB, TPB, 0, stream>>>(
        conv_buf, ss, xa, 16, H, W, n);
  }
  // ---- Layer 1: CI=16, CO=32, 64x512, pool -> xb2 (NHWC), dfc_og OGC=1
  {
    const int H = 64, W = 512;
    off_conv<16, 256><<<B * 3 * (H * W / 256), 256, 0, stream>>>(
        xa, wpk + OWO1, boff[1], off_buf, B, H, W);
    dfc_og<16, 32, 1, 256><<<B * (H * W / 256), 256, 0, stream>>>(
        xa, off_buf, wpk + OWM1, conv_buf, B, H, W);
    bn_head(conv_buf, 32, H, W, 32, g[1], bb[1], 1);
    int n = B * 32 * (H / 2) * (W / 2);
    bn_apply_pool_nhwc_kernel<<<n / TPB, TPB, 0, stream>>>(
        conv_buf, ss, xb2, 32, H, W, n);
  }
  // ---- Layer 2: CI=32, CO=48, 32x256, pool -> xa (NHWC), dfc_og OGC=2
  {
    const int H = 32, W = 256;
    off_conv<32, 256><<<B * 3 * (H * W / 256), 256, 0, stream>>>(
        xb2, wpk + OWO2, boff[2], off_buf, B, H, W);
    dfc_og<32, 48, 2, 256><<<B * (H * W / 256) * 2, 256, 0, stream>>>(
        xb2, off_buf, wpk + OWM2, conv_buf, B, H, W);
    bn_head(conv_buf, 48, H, W, 16, g[2], bb[2], 2);
    int n = B * 48 * (H / 2) * (W / 2);
    bn_apply_pool_nhwc_kernel<<<n / TPB, TPB, 0, stream>>>(
        conv_buf, ss, xa, 48, H, W, n);
  }
  // ---- Layer 3: CI=48, CO=64, 16x128, no pool -> xb2 (NHWC), dfc_wave8
  {
    const int H = 16, W = 128;
    off_conv<48, 64><<<B * 3 * (H * W / 64), 64, 0, stream>>>(
        xa, wpk + OWO3, boff[3], off_buf, B, H, W);
    dfc_wave8<48, 64><<<B * (H * W / 64), 512, 0, stream>>>(
        xa, off_buf, wpk + OWM3, conv_buf, B, H, W);
    bn_head(conv_buf, 64, H, W, 8, g[3], bb[3], 3);
    int n = B * 64 * H * W;
    bn_apply_nhwc_kernel<<<n / TPB, TPB, 0, stream>>>(
        conv_buf, ss, xb2, 64, H, W, n);
  }
  // ---- Layer 4: CI=64, CO=80, 16x128, no pool -> d_out (NCHW), dfc_wave8
  {
    const int H = 16, W = 128;
    off_conv<64, 64><<<B * 3 * (H * W / 64), 64, 0, stream>>>(
        xb2, wpk + OWO4, boff[4], off_buf, B, H, W);
    dfc_wave8<64, 80><<<B * (H * W / 64), 512, 0, stream>>>(
        xb2, off_buf, wpk + OWM4, conv_buf, B, H, W);
    bn_head(conv_buf, 80, H, W, 8, g[4], bb[4], 4);
    int n = B * 80 * H * W;
    bn_apply_kernel<<<n / TPB, TPB, 0, stream>>>(
        conv_buf, ss, (float*)d_out, 80, H * W, n);
  }
}

// Round 15
// 570.597 us; speedup vs baseline: 1.0029x; 1.0029x over previous
//
#include <hip/hip_runtime.h>
#include <math.h>

#define TPB 256

// ---------------------------------------------------------------------------
// Geometry:
//   x: [8, 1, 128, 1024] f32
//   L0: CI=1,  CO=16, 128x1024, pool -> 64x512   (fused offsets)
//   L1: CI=16, CO=32, 64x512,   pool -> 32x256   dfc_og OGC=1
//   L2: CI=32, CO=48, 32x256,   pool -> 16x128   dfc_og OGC=2
//   L3: CI=48, CO=64, 16x128,   no pool          dfc_og OGC=4, NKG=3 (R15)
//   L4: CI=64, CO=80, 16x128,   no pool -> d_out dfc_og OGC=5, NKG=3 (R15)
//
// R15: tail layers are latency-bound with a parallelism cap (px*OGC threads
// = 5 waves/CU; R11 showed OGC scaling adds lookups 1:1). Tap-split NKG=3
// triples waves/CU with ZERO extra gather lookups; 3 partial outputs are
// summed inside BN (L2-resident, ~free). R9/R12/R13/R14 lesson: LDS-staged
// gather sharing loses to latency exposure at these grid sizes — abandoned.
// Kept: NHWC activations, wave-uniform s_load packed weights, XCD swizzle,
// no launch_bounds min-wave cap, bounded unrolls, no reg pipeline arrays.
// ---------------------------------------------------------------------------

// Packed-weight workspace offsets (floats)
#define OWM0 0
#define OWM1 144
#define OWM2 4752
#define OWM3 18576
#define OWM4 46224
#define OWO0 92304
#define OWO1 92484
#define OWO2 95940
#define OWO3 102852
#define OWO4 113220
#define PACK_FLOATS 131072

struct PackSrc { const float* p[10]; };  // 0-4: wmain, 5-9: woff

__global__ void pack_weights(PackSrc s, float* __restrict__ dst) {
  int seg = blockIdx.y;
  int idx = blockIdx.x * TPB + threadIdx.x;
  int CI, CO, ow;
  if (seg < 5) {
    if (seg == 0)      { CI = 1;  CO = 16; ow = OWM0; }
    else if (seg == 1) { CI = 16; CO = 32; ow = OWM1; }
    else if (seg == 2) { CI = 32; CO = 48; ow = OWM2; }
    else if (seg == 3) { CI = 48; CO = 64; ow = OWM3; }
    else               { CI = 64; CO = 80; ow = OWM4; }
    int n = 9 * CI * CO;
    if (idx >= n) return;
    int o = idx % CO, rest = idx / CO;
    int c = rest % CI, k = rest / CI;
    dst[ow + idx] = s.p[seg][((size_t)o * CI + c) * 9 + k];
  } else if (seg == 5) {
    if (idx >= 180) return;
    int j = idx % 20, t = idx / 20;
    dst[OWO0 + idx] = (j < 18) ? s.p[5][j * 9 + t] : 0.f;
  } else {
    if (seg == 6)      { CI = 16; ow = OWO1; }
    else if (seg == 7) { CI = 32; ow = OWO2; }
    else if (seg == 8) { CI = 48; ow = OWO3; }
    else               { CI = 64; ow = OWO4; }
    int n = 3 * CI * 9 * 8;
    if (idx >= n) return;
    int u = idx % 8, r = idx / 8;
    int t = r % 9, c = (r / 9) % CI, jg = r / (9 * CI);
    dst[ow + idx] = (u < 6) ? s.p[seg][((size_t)(jg * 6 + u) * CI + c) * 9 + t] : 0.f;
  }
}

// XCD-aware swizzle: nwg % 8 == 0 at every launch site.
__device__ __forceinline__ int xcd_swz(int bid, int nwg) {
  return (bid & 7) * (nwg >> 3) + (bid >> 3);
}

// ---------------------------------------------------------------------------
// L0: CI=1 (NCHW==NHWC) -> fused offsets + deform conv, out NCHW.
// ---------------------------------------------------------------------------
__global__ __launch_bounds__(TPB) void dfc_fused0(
    const float* __restrict__ x, const float* __restrict__ woP,   // [9][20]
    const float* __restrict__ boff, const float* __restrict__ wmP, // [9][16]
    float* __restrict__ out, int B, int H, int W) {
  const int idx = xcd_swz(blockIdx.x, gridDim.x) * TPB + threadIdx.x;
  const int HW = H * W;
  const int w = idx % W;
  const int h = (idx / W) % H;
  const int b = idx / HW;
  const float* xp = x + (size_t)b * HW;

  float xv[9];
#pragma unroll
  for (int t = 0; t < 9; t++) {
    int yy = h - 1 + t / 3, xx = w - 1 + t % 3;
    xv[t] = (yy >= 0 && yy < H && xx >= 0 && xx < W) ? xp[yy * W + xx] : 0.f;
  }

  float offv[18];
#pragma unroll
  for (int j = 0; j < 18; j++) offv[j] = boff[j];
#pragma unroll
  for (int t = 0; t < 9; t++) {
    const float* wr = &woP[t * 20];
#pragma unroll
    for (int j = 0; j < 18; j++) offv[j] = fmaf(xv[t], wr[j], offv[j]);
  }

  float acc[16];
#pragma unroll
  for (int o = 0; o < 16; o++) acc[o] = 0.f;

#pragma unroll
  for (int k = 0; k < 9; k++) {
    float py = (float)(h - 1 + k / 3) + offv[2 * k];
    float px = (float)(w - 1 + k % 3) + offv[2 * k + 1];
    float fy = floorf(py), fx = floorf(px);
    float wy = py - fy, wx = px - fx;
    int y0 = (int)fy, x0 = (int)fx;
    int y1 = y0 + 1, x1 = x0 + 1;
    bool vy0 = (y0 >= 0) & (y0 < H), vy1 = (y1 >= 0) & (y1 < H);
    bool vx0 = (x0 >= 0) & (x0 < W), vx1 = (x1 >= 0) & (x1 < W);
    int yc0 = min(max(y0, 0), H - 1), yc1 = min(max(y1, 0), H - 1);
    int xc0 = min(max(x0, 0), W - 1), xc1 = min(max(x1, 0), W - 1);
    float w00 = (vy0 && vx0) ? (1.f - wy) * (1.f - wx) : 0.f;
    float w01 = (vy0 && vx1) ? (1.f - wy) * wx : 0.f;
    float w10 = (vy1 && vx0) ? wy * (1.f - wx) : 0.f;
    float w11 = (vy1 && vx1) ? wy * wx : 0.f;
    float sv = xp[yc0 * W + xc0] * w00 + xp[yc0 * W + xc1] * w01
             + xp[yc1 * W + xc0] * w10 + xp[yc1 * W + xc1] * w11;
    const float* wr = &wmP[k * 16];
#pragma unroll
    for (int o = 0; o < 16; o++) acc[o] = fmaf(sv, wr[o], acc[o]);
  }

  float* op = out + (size_t)b * 16 * HW + h * W + w;
#pragma unroll
  for (int o = 0; o < 16; o++) op[(size_t)o * HW] = acc[o];
}

// ---------------------------------------------------------------------------
// Offset conv (L1-L4): x NHWC, per tap CI/4 float4 loads, s_load weights.
// ---------------------------------------------------------------------------
template<int CI, int TPBK>
__global__ __launch_bounds__(TPBK) void off_conv(
    const float* __restrict__ x, const float* __restrict__ wP,
    const float* __restrict__ boff, float* __restrict__ off,
    int B, int H, int W) {
  const int HW = H * W;
  const int npb = HW / TPBK;
  const int bid = xcd_swz(blockIdx.x, gridDim.x);
  const int pxb = bid % npb;
  const int jg = (bid / npb) % 3;
  const int b = bid / (3 * npb);
  const int px = pxb * TPBK + threadIdx.x;
  const int w = px % W, h = px / W;
  const float* xb = x + (size_t)b * HW * CI;
  const float* wj = wP + (size_t)jg * CI * 9 * 8;

  float acc[6];
#pragma unroll
  for (int u = 0; u < 6; u++) acc[u] = boff[jg * 6 + u];

#pragma unroll 1
  for (int t = 0; t < 9; t++) {
    int yy = h - 1 + t / 3, xx = w - 1 + t % 3;
    bool vld = (yy >= 0 && yy < H && xx >= 0 && xx < W);
    int a = vld ? (yy * W + xx) : 0;
    const float* xp = xb + (size_t)a * CI;
    const float* wt = wj + t * 8;
#pragma unroll 4
    for (int cg = 0; cg < CI / 4; cg++) {
      float4 v = *(const float4*)(xp + cg * 4);
      float s0 = vld ? v.x : 0.f;
      float s1 = vld ? v.y : 0.f;
      float s2 = vld ? v.z : 0.f;
      float s3 = vld ? v.w : 0.f;
      const float* w0 = wt + (size_t)cg * 4 * 72;
#pragma unroll
      for (int u = 0; u < 6; u++) {
        float a0 = fmaf(s0, w0[u], acc[u]);
        float a1 = fmaf(s1, w0[72 + u], a0);
        float a2 = fmaf(s2, w0[144 + u], a1);
        acc[u] = fmaf(s3, w0[216 + u], a2);
      }
    }
  }
#pragma unroll
  for (int u = 0; u < 6; u++)
    off[((size_t)b * 18 + jg * 6 + u) * HW + px] = acc[u];
}

// ---------------------------------------------------------------------------
// Deform conv, og-split per-pixel-thread, optional tap-split NKG (9%NKG==0).
// kg writes to partial plane kg (stride B*CO*HW); BN sums the partials.
// ---------------------------------------------------------------------------
template<int CI, int CO, int OGC, int TPBK, int NKG>
__global__ __launch_bounds__(TPBK) void dfc_og(
    const float* __restrict__ x, const float* __restrict__ off,
    const float* __restrict__ wP, float* __restrict__ out,
    int B, int H, int W) {
  constexpr int COG = CO / OGC;
  constexpr int KPG = 9 / NKG;
  const int HW = H * W;
  const int npb = HW / TPBK;
  const int bid = xcd_swz(blockIdx.x, gridDim.x);
  const int og = bid % OGC;
  int r = bid / OGC;
  const int pxb = r % npb; r /= npb;
  const int kg = r % NKG;
  const int b = r / NKG;
  const int px = pxb * TPBK + threadIdx.x;
  const int w = px % W, h = px / W;
  const float* xb = x + (size_t)b * HW * CI;   // NHWC

  float offv[2 * KPG];
  const float* ob = off + (size_t)b * 18 * HW + px;
#pragma unroll
  for (int j = 0; j < 2 * KPG; j++)
    offv[j] = ob[(size_t)(kg * 2 * KPG + j) * HW];

  float acc[COG];
#pragma unroll
  for (int o = 0; o < COG; o++) acc[o] = 0.f;

#pragma unroll
  for (int kk = 0; kk < KPG; kk++) {
    const int k = kg * KPG + kk;
    float py = (float)(h - 1 + k / 3) + offv[2 * kk];
    float pxx = (float)(w - 1 + k % 3) + offv[2 * kk + 1];
    float fy = floorf(py), fx = floorf(pxx);
    float wy = py - fy, wx = pxx - fx;
    int y0 = (int)fy, x0 = (int)fx;
    int y1 = y0 + 1, x1 = x0 + 1;
    bool vy0 = (y0 >= 0) & (y0 < H), vy1 = (y1 >= 0) & (y1 < H);
    bool vx0 = (x0 >= 0) & (x0 < W), vx1 = (x1 >= 0) & (x1 < W);
    int yc0 = min(max(y0, 0), H - 1), yc1 = min(max(y1, 0), H - 1);
    int xc0 = min(max(x0, 0), W - 1), xc1 = min(max(x1, 0), W - 1);
    float w00 = (vy0 && vx0) ? (1.f - wy) * (1.f - wx) : 0.f;
    float w01 = (vy0 && vx1) ? (1.f - wy) * wx : 0.f;
    float w10 = (vy1 && vx0) ? wy * (1.f - wx) : 0.f;
    float w11 = (vy1 && vx1) ? wy * wx : 0.f;
    const float* p00 = xb + (size_t)(yc0 * W + xc0) * CI;
    const float* p01 = xb + (size_t)(yc0 * W + xc1) * CI;
    const float* p10 = xb + (size_t)(yc1 * W + xc0) * CI;
    const float* p11 = xb + (size_t)(yc1 * W + xc1) * CI;
#pragma unroll 2
    for (int cg = 0; cg < CI / 4; cg++) {
      float4 v00 = *(const float4*)(p00 + cg * 4);
      float4 v01 = *(const float4*)(p01 + cg * 4);
      float4 v10 = *(const float4*)(p10 + cg * 4);
      float4 v11 = *(const float4*)(p11 + cg * 4);
      float s0 = v00.x * w00 + v01.x * w01 + v10.x * w10 + v11.x * w11;
      float s1 = v00.y * w00 + v01.y * w01 + v10.y * w10 + v11.y * w11;
      float s2 = v00.z * w00 + v01.z * w01 + v10.z * w10 + v11.z * w11;
      float s3 = v00.w * w00 + v01.w * w01 + v10.w * w10 + v11.w * w11;
      const float* wr = wP + (size_t)(k * CI + cg * 4) * CO + og * COG;
#pragma unroll
      for (int o = 0; o < COG; o++) {
        float a0 = fmaf(s0, wr[o], acc[o]);
        float a1 = fmaf(s1, wr[CO + o], a0);
        float a2 = fmaf(s2, wr[2 * CO + o], a1);
        acc[o] = fmaf(s3, wr[3 * CO + o], a2);
      }
    }
  }

  float* op = out + (size_t)kg * B * CO * HW
            + ((size_t)b * CO + og * COG) * HW + px;
#pragma unroll
  for (int o = 0; o < COG; o++) op[(size_t)o * HW] = acc[o];
}

// ---------------------------------------------------------------------------
// BatchNorm (training stats, y NCHW [+NP partial planes]) + LeakyReLU.
// ---------------------------------------------------------------------------
template<int NP>
__global__ void bn_stats_kernel(const float* __restrict__ y, size_t ps,
                                double* __restrict__ st,
                                int B, int C, int HW, int NB) {
  int c = blockIdx.x / NB;
  int sl = blockIdx.x % NB;
  int tid = threadIdx.x;
  double s = 0.0, s2 = 0.0;
  int HW4 = HW >> 2;
  for (int b = 0; b < B; b++) {
    size_t base = ((size_t)b * C + c) * HW;
    for (int i = sl * TPB + tid; i < HW4; i += NB * TPB) {
      float4 v = *(const float4*)(y + base + 4 * (size_t)i);
      if (NP > 1) {
        float4 v1 = *(const float4*)(y + ps + base + 4 * (size_t)i);
        float4 v2 = *(const float4*)(y + 2 * ps + base + 4 * (size_t)i);
        v.x += v1.x + v2.x; v.y += v1.y + v2.y;
        v.z += v1.z + v2.z; v.w += v1.w + v2.w;
      }
      s += (double)v.x + (double)v.y + (double)v.z + (double)v.w;
      s2 += (double)v.x * v.x + (double)v.y * v.y
          + (double)v.z * v.z + (double)v.w * v.w;
    }
  }
  __shared__ double rs[TPB], rq[TPB];
  rs[tid] = s;
  rq[tid] = s2;
  __syncthreads();
  for (int o = TPB / 2; o > 0; o >>= 1) {
    if (tid < o) { rs[tid] += rs[tid + o]; rq[tid] += rq[tid + o]; }
    __syncthreads();
  }
  if (tid == 0) {
    atomicAdd(&st[2 * c], rs[0]);
    atomicAdd(&st[2 * c + 1], rq[0]);
  }
}

__global__ void bn_finalize_kernel(const double* __restrict__ st,
                                   const float* __restrict__ g,
                                   const float* __restrict__ bb,
                                   float* __restrict__ ss, int C, int N) {
  int c = threadIdx.x;
  if (c >= C) return;
  double mean = st[2 * c] / N;
  double var = st[2 * c + 1] / N - mean * mean;
  float inv = (float)(1.0 / sqrt(var + 1e-5));
  float sc = g[c] * inv;
  ss[c] = sc;
  ss[C + c] = bb[c] - (float)mean * sc;
}

// NCHW -> NCHW (final output), NP partial planes summed
template<int NP>
__global__ void bn_apply_kernel(const float* __restrict__ y, size_t ps,
                                const float* __restrict__ ss,
                                float* __restrict__ out, int C, int HW, int n) {
  int i = blockIdx.x * TPB + threadIdx.x;
  if (i >= n) return;
  float yv = y[i];
  if (NP > 1) yv += y[ps + i] + y[2 * ps + i];
  int c = (i / HW) % C;
  float v = fmaf(yv, ss[c], ss[C + c]);
  out[i] = v > 0.f ? v : 0.01f * v;
}

// NCHW -> NHWC (no pool; L3), NP partial planes summed
template<int NP>
__global__ void bn_apply_nhwc_kernel(const float* __restrict__ y, size_t ps,
                                     const float* __restrict__ ss,
                                     float* __restrict__ out,
                                     int C, int H, int W, int n) {
  int i = blockIdx.x * TPB + threadIdx.x;
  if (i >= n) return;
  int c = i % C;
  int pix = i / C;
  int w = pix % W;
  int h = (pix / W) % H;
  int b = pix / (W * H);
  size_t a = (((size_t)b * C + c) * H + h) * W + w;
  float yv = y[a];
  if (NP > 1) yv += y[ps + a] + y[2 * ps + a];
  float v = fmaf(yv, ss[c], ss[C + c]);
  out[i] = v > 0.f ? v : 0.01f * v;
}

// NCHW -> 2x2 maxpool -> NHWC (L0,L1,L2)
__global__ void bn_apply_pool_nhwc_kernel(const float* __restrict__ y,
                                          const float* __restrict__ ss,
                                          float* __restrict__ out,
                                          int C, int H, int W, int n) {
  int i = blockIdx.x * TPB + threadIdx.x;
  if (i >= n) return;
  int Wp = W >> 1, Hp = H >> 1;
  int c = i % C;
  int pw = (i / C) % Wp;
  int ph = (i / C / Wp) % Hp;
  int b = i / (C * Wp * Hp);
  const float* yp = y + (((size_t)b * C + c) * H + 2 * ph) * W + 2 * pw;
  float sc = ss[c], sh = ss[C + c];
  float v0 = fmaf(yp[0], sc, sh);     v0 = v0 > 0.f ? v0 : 0.01f * v0;
  float v1 = fmaf(yp[1], sc, sh);     v1 = v1 > 0.f ? v1 : 0.01f * v1;
  float v2 = fmaf(yp[W], sc, sh);     v2 = v2 > 0.f ? v2 : 0.01f * v2;
  float v3 = fmaf(yp[W + 1], sc, sh); v3 = v3 > 0.f ? v3 : 0.01f * v3;
  out[i] = fmaxf(fmaxf(v0, v1), fmaxf(v2, v3));
}

extern "C" void kernel_launch(void* const* d_in, const int* in_sizes, int n_in,
                              void* d_out, int out_size, void* d_ws, size_t ws_size,
                              hipStream_t stream) {
  const float* x = (const float*)d_in[0];
  const float *woff[5], *boff[5], *wm[5], *g[5], *bb[5];
  for (int i = 0; i < 5; i++) {
    woff[i] = (const float*)d_in[1 + 5 * i + 0];
    boff[i] = (const float*)d_in[1 + 5 * i + 1];
    wm[i]   = (const float*)d_in[1 + 5 * i + 2];
    g[i]    = (const float*)d_in[1 + 5 * i + 3];
    bb[i]   = (const float*)d_in[1 + 5 * i + 4];
  }

  const size_t need =
      (size_t)(16777216 + 4718592 + 4194304 + 2097152 + PACK_FLOATS) * 4 + 6400 + 640;
  if (ws_size < need) return;

  float* conv_buf = (float*)d_ws;          // NCHW conv outputs / tail partials
  float* off_buf = conv_buf + 16777216;    // offsets [b][18][HW]
  float* xa = off_buf + 4718592;           // x1 / x3 (NHWC)
  float* xb2 = xa + 4194304;               // x2 / x4 (NHWC)
  float* wpk = xb2 + 2097152;              // packed weights
  double* st = (double*)(wpk + PACK_FLOATS);   // 5 x 160 doubles
  float* ss = (float*)(st + 800);

  const int B = 8;

  {
    PackSrc psrc;
    for (int i = 0; i < 5; i++) { psrc.p[i] = wm[i]; psrc.p[5 + i] = woff[i]; }
    pack_weights<<<dim3(180, 10), TPB, 0, stream>>>(psrc, wpk);
    hipMemsetAsync(st, 0, 800 * sizeof(double), stream);   // all layers' stats
  }

  // ---- Layer 0: CI=1, CO=16, 128x1024, fused offsets, pool -> xa (NHWC)
  {
    const int H = 128, W = 1024;
    dfc_fused0<<<B * H * W / TPB, TPB, 0, stream>>>(
        x, wpk + OWO0, boff[0], wpk + OWM0, conv_buf, B, H, W);
    bn_stats_kernel<1><<<16 * 32, TPB, 0, stream>>>(conv_buf, 0, st, B, 16, H * W, 32);
    bn_finalize_kernel<<<1, TPB, 0, stream>>>(st, g[0], bb[0], ss, 16, B * H * W);
    int n = B * 16 * (H / 2) * (W / 2);
    bn_apply_pool_nhwc_kernel<<<n / TPB, TPB, 0, stream>>>(
        conv_buf, ss, xa, 16, H, W, n);
  }
  // ---- Layer 1: CI=16, CO=32, 64x512, pool -> xb2 (NHWC), dfc_og OGC=1
  {
    const int H = 64, W = 512;
    off_conv<16, 256><<<B * 3 * (H * W / 256), 256, 0, stream>>>(
        xa, wpk + OWO1, boff[1], off_buf, B, H, W);
    dfc_og<16, 32, 1, 256, 1><<<B * (H * W / 256), 256, 0, stream>>>(
        xa, off_buf, wpk + OWM1, conv_buf, B, H, W);
    bn_stats_kernel<1><<<32 * 32, TPB, 0, stream>>>(conv_buf, 0, st + 160, B, 32, H * W, 32);
    bn_finalize_kernel<<<1, TPB, 0, stream>>>(st + 160, g[1], bb[1], ss, 32, B * H * W);
    int n = B * 32 * (H / 2) * (W / 2);
    bn_apply_pool_nhwc_kernel<<<n / TPB, TPB, 0, stream>>>(
        conv_buf, ss, xb2, 32, H, W, n);
  }
  // ---- Layer 2: CI=32, CO=48, 32x256, pool -> xa (NHWC), dfc_og OGC=2
  {
    const int H = 32, W = 256;
    off_conv<32, 256><<<B * 3 * (H * W / 256), 256, 0, stream>>>(
        xb2, wpk + OWO2, boff[2], off_buf, B, H, W);
    dfc_og<32, 48, 2, 256, 1><<<B * (H * W / 256) * 2, 256, 0, stream>>>(
        xb2, off_buf, wpk + OWM2, conv_buf, B, H, W);
    bn_stats_kernel<1><<<48 * 16, TPB, 0, stream>>>(conv_buf, 0, st + 320, B, 48, H * W, 16);
    bn_finalize_kernel<<<1, TPB, 0, stream>>>(st + 320, g[2], bb[2], ss, 48, B * H * W);
    int n = B * 48 * (H / 2) * (W / 2);
    bn_apply_pool_nhwc_kernel<<<n / TPB, TPB, 0, stream>>>(
        conv_buf, ss, xa, 48, H, W, n);
  }
  // ---- Layer 3: CI=48, CO=64, 16x128, no pool -> xb2 (NHWC), OGC=4, NKG=3
  {
    const int H = 16, W = 128;
    const size_t ps = (size_t)B * 64 * H * W;
    off_conv<48, 64><<<B * 3 * (H * W / 64), 64, 0, stream>>>(
        xa, wpk + OWO3, boff[3], off_buf, B, H, W);
    dfc_og<48, 64, 4, 64, 3><<<B * 3 * (H * W / 64) * 4, 64, 0, stream>>>(
        xa, off_buf, wpk + OWM3, conv_buf, B, H, W);
    bn_stats_kernel<3><<<64 * 8, TPB, 0, stream>>>(conv_buf, ps, st + 480, B, 64, H * W, 8);
    bn_finalize_kernel<<<1, TPB, 0, stream>>>(st + 480, g[3], bb[3], ss, 64, B * H * W);
    int n = B * 64 * H * W;
    bn_apply_nhwc_kernel<3><<<n / TPB, TPB, 0, stream>>>(
        conv_buf, ps, ss, xb2, 64, H, W, n);
  }
  // ---- Layer 4: CI=64, CO=80, 16x128, no pool -> d_out (NCHW), OGC=5, NKG=3
  {
    const int H = 16, W = 128;
    const size_t ps = (size_t)B * 80 * H * W;
    off_conv<64, 64><<<B * 3 * (H * W / 64), 64, 0, stream>>>(
        xb2, wpk + OWO4, boff[4], off_buf, B, H, W);
    dfc_og<64, 80, 5, 64, 3><<<B * 3 * (H * W / 64) * 5, 64, 0, stream>>>(
        xb2, off_buf, wpk + OWM4, conv_buf, B, H, W);
    bn_stats_kernel<3><<<80 * 8, TPB, 0, stream>>>(conv_buf, ps, st + 640, B, 80, H * W, 8);
    bn_finalize_kernel<<<1, TPB, 0, stream>>>(st + 640, g[4], bb[4], ss, 80, B * H * W);
    int n = B * 80 * H * W;
    bn_apply_kernel<3><<<n / TPB, TPB, 0, stream>>>(
        conv_buf, ps, ss, (float*)d_out, 80, H * W, n);
  }
}

// Round 16
// 506.967 us; speedup vs baseline: 1.1287x; 1.1255x over previous
//
#include <hip/hip_runtime.h>
#include <math.h>

#define TPB 256

// ---------------------------------------------------------------------------
// Geometry:
//   x: [8, 1, 128, 1024] f32
//   L0: CI=1,  CO=16, 128x1024, pool -> 64x512   (fused offsets)
//   L1: CI=16, CO=32, 64x512,   pool -> 32x256   off18 + dfc_og OGC=1
//   L2: CI=32, CO=48, 32x256,   pool -> 16x128   off18 + dfc_og OGC=2
//   L3: CI=48, CO=64, 16x128,   no pool          off(jg) + dfc_og OGC=4
//   L4: CI=64, CO=80, 16x128,   no pool -> d_out off(jg) + dfc_og OGC=5
//
// R16 = exact R10 pipeline (best measured, 492us) + off_conv jg-merge on
// L1/L2: one thread computes all 18 offset channels (acc[18], no spill)
// -> tap gathers issued once instead of 3x (TA line-lookups /3; FMA total
// unchanged). Tail dfc_og untouched: R11-R15 all lost to it (OGC scaling,
// LDS-sharing x3, tap-split) — its 85us is the structural local optimum.
// Kept: NHWC activations, wave-uniform s_load packed weights, XCD swizzle,
// no launch_bounds min-wave cap, bounded unrolls, no reg pipeline arrays.
// ---------------------------------------------------------------------------

// Packed-weight workspace offsets (floats)
#define OWM0 0
#define OWM1 144
#define OWM2 4752
#define OWM3 18576
#define OWM4 46224
#define OWO0 92304
#define OWO1 92484
#define OWO2 95940
#define OWO3 102852
#define OWO4 113220
#define PACK_FLOATS 131072

struct PackSrc { const float* p[10]; };  // 0-4: wmain, 5-9: woff

__global__ void pack_weights(PackSrc s, float* __restrict__ dst) {
  int seg = blockIdx.y;
  int idx = blockIdx.x * TPB + threadIdx.x;
  int CI, CO, ow;
  if (seg < 5) {
    if (seg == 0)      { CI = 1;  CO = 16; ow = OWM0; }
    else if (seg == 1) { CI = 16; CO = 32; ow = OWM1; }
    else if (seg == 2) { CI = 32; CO = 48; ow = OWM2; }
    else if (seg == 3) { CI = 48; CO = 64; ow = OWM3; }
    else               { CI = 64; CO = 80; ow = OWM4; }
    int n = 9 * CI * CO;
    if (idx >= n) return;
    int o = idx % CO, rest = idx / CO;
    int c = rest % CI, k = rest / CI;
    dst[ow + idx] = s.p[seg][((size_t)o * CI + c) * 9 + k];
  } else if (seg == 5) {
    if (idx >= 180) return;
    int j = idx % 20, t = idx / 20;
    dst[OWO0 + idx] = (j < 18) ? s.p[5][j * 9 + t] : 0.f;
  } else {
    if (seg == 6)      { CI = 16; ow = OWO1; }
    else if (seg == 7) { CI = 32; ow = OWO2; }
    else if (seg == 8) { CI = 48; ow = OWO3; }
    else               { CI = 64; ow = OWO4; }
    int n = 3 * CI * 9 * 8;
    if (idx >= n) return;
    int u = idx % 8, r = idx / 8;
    int t = r % 9, c = (r / 9) % CI, jg = r / (9 * CI);
    dst[ow + idx] = (u < 6) ? s.p[seg][((size_t)(jg * 6 + u) * CI + c) * 9 + t] : 0.f;
  }
}

// XCD-aware swizzle: nwg % 8 == 0 at every launch site.
__device__ __forceinline__ int xcd_swz(int bid, int nwg) {
  return (bid & 7) * (nwg >> 3) + (bid >> 3);
}

// ---------------------------------------------------------------------------
// L0: CI=1 (NCHW==NHWC) -> fused offsets + deform conv, out NCHW.
// ---------------------------------------------------------------------------
__global__ __launch_bounds__(TPB) void dfc_fused0(
    const float* __restrict__ x, const float* __restrict__ woP,   // [9][20]
    const float* __restrict__ boff, const float* __restrict__ wmP, // [9][16]
    float* __restrict__ out, int B, int H, int W) {
  const int idx = xcd_swz(blockIdx.x, gridDim.x) * TPB + threadIdx.x;
  const int HW = H * W;
  const int w = idx % W;
  const int h = (idx / W) % H;
  const int b = idx / HW;
  const float* xp = x + (size_t)b * HW;

  float xv[9];
#pragma unroll
  for (int t = 0; t < 9; t++) {
    int yy = h - 1 + t / 3, xx = w - 1 + t % 3;
    xv[t] = (yy >= 0 && yy < H && xx >= 0 && xx < W) ? xp[yy * W + xx] : 0.f;
  }

  float offv[18];
#pragma unroll
  for (int j = 0; j < 18; j++) offv[j] = boff[j];
#pragma unroll
  for (int t = 0; t < 9; t++) {
    const float* wr = &woP[t * 20];
#pragma unroll
    for (int j = 0; j < 18; j++) offv[j] = fmaf(xv[t], wr[j], offv[j]);
  }

  float acc[16];
#pragma unroll
  for (int o = 0; o < 16; o++) acc[o] = 0.f;

#pragma unroll
  for (int k = 0; k < 9; k++) {
    float py = (float)(h - 1 + k / 3) + offv[2 * k];
    float px = (float)(w - 1 + k % 3) + offv[2 * k + 1];
    float fy = floorf(py), fx = floorf(px);
    float wy = py - fy, wx = px - fx;
    int y0 = (int)fy, x0 = (int)fx;
    int y1 = y0 + 1, x1 = x0 + 1;
    bool vy0 = (y0 >= 0) & (y0 < H), vy1 = (y1 >= 0) & (y1 < H);
    bool vx0 = (x0 >= 0) & (x0 < W), vx1 = (x1 >= 0) & (x1 < W);
    int yc0 = min(max(y0, 0), H - 1), yc1 = min(max(y1, 0), H - 1);
    int xc0 = min(max(x0, 0), W - 1), xc1 = min(max(x1, 0), W - 1);
    float w00 = (vy0 && vx0) ? (1.f - wy) * (1.f - wx) : 0.f;
    float w01 = (vy0 && vx1) ? (1.f - wy) * wx : 0.f;
    float w10 = (vy1 && vx0) ? wy * (1.f - wx) : 0.f;
    float w11 = (vy1 && vx1) ? wy * wx : 0.f;
    float sv = xp[yc0 * W + xc0] * w00 + xp[yc0 * W + xc1] * w01
             + xp[yc1 * W + xc0] * w10 + xp[yc1 * W + xc1] * w11;
    const float* wr = &wmP[k * 16];
#pragma unroll
    for (int o = 0; o < 16; o++) acc[o] = fmaf(sv, wr[o], acc[o]);
  }

  float* op = out + (size_t)b * 16 * HW + h * W + w;
#pragma unroll
  for (int o = 0; o < 16; o++) op[(size_t)o * HW] = acc[o];
}

// ---------------------------------------------------------------------------
// Offset conv, jg-split (L3/L4 small grids): x NHWC, CI/4 float4 per tap,
// s_load weights, acc[6].
// ---------------------------------------------------------------------------
template<int CI, int TPBK>
__global__ __launch_bounds__(TPBK) void off_conv(
    const float* __restrict__ x, const float* __restrict__ wP,
    const float* __restrict__ boff, float* __restrict__ off,
    int B, int H, int W) {
  const int HW = H * W;
  const int npb = HW / TPBK;
  const int bid = xcd_swz(blockIdx.x, gridDim.x);
  const int pxb = bid % npb;
  const int jg = (bid / npb) % 3;
  const int b = bid / (3 * npb);
  const int px = pxb * TPBK + threadIdx.x;
  const int w = px % W, h = px / W;
  const float* xb = x + (size_t)b * HW * CI;
  const float* wj = wP + (size_t)jg * CI * 72;

  float acc[6];
#pragma unroll
  for (int u = 0; u < 6; u++) acc[u] = boff[jg * 6 + u];

#pragma unroll 1
  for (int t = 0; t < 9; t++) {
    int yy = h - 1 + t / 3, xx = w - 1 + t % 3;
    bool vld = (yy >= 0 && yy < H && xx >= 0 && xx < W);
    int a = vld ? (yy * W + xx) : 0;
    const float* xp = xb + (size_t)a * CI;
    const float* wt = wj + t * 8;
#pragma unroll 4
    for (int cg = 0; cg < CI / 4; cg++) {
      float4 v = *(const float4*)(xp + cg * 4);
      float s0 = vld ? v.x : 0.f;
      float s1 = vld ? v.y : 0.f;
      float s2 = vld ? v.z : 0.f;
      float s3 = vld ? v.w : 0.f;
      const float* w0 = wt + (size_t)cg * 4 * 72;
#pragma unroll
      for (int u = 0; u < 6; u++) {
        float a0 = fmaf(s0, w0[u], acc[u]);
        float a1 = fmaf(s1, w0[72 + u], a0);
        float a2 = fmaf(s2, w0[144 + u], a1);
        acc[u] = fmaf(s3, w0[216 + u], a2);
      }
    }
  }
#pragma unroll
  for (int u = 0; u < 6; u++)
    off[((size_t)b * 18 + jg * 6 + u) * HW + px] = acc[u];
}

// ---------------------------------------------------------------------------
// Offset conv, jg-MERGED (L1/L2): one thread = one pixel, all 18 channels.
// Tap gathers issued ONCE (was 3x with jg split) -> TA lookups /3.
// acc[18] + <=2 float4 in flight: ~44 VGPR, no spill.
// ---------------------------------------------------------------------------
template<int CI, int TPBK>
__global__ __launch_bounds__(TPBK) void off_conv18(
    const float* __restrict__ x, const float* __restrict__ wP,  // [3][CI*9][8]
    const float* __restrict__ boff, float* __restrict__ off,
    int B, int H, int W) {
  const int HW = H * W;
  const int npb = HW / TPBK;
  const int bid = xcd_swz(blockIdx.x, gridDim.x);
  const int pxb = bid % npb;
  const int b = bid / npb;
  const int px = pxb * TPBK + threadIdx.x;
  const int w = px % W, h = px / W;
  const float* xb = x + (size_t)b * HW * CI;

  float acc[18];
#pragma unroll
  for (int j = 0; j < 18; j++) acc[j] = boff[j];

#pragma unroll 1
  for (int t = 0; t < 9; t++) {
    int yy = h - 1 + t / 3, xx = w - 1 + t % 3;
    bool vld = (yy >= 0 && yy < H && xx >= 0 && xx < W);
    int a = vld ? (yy * W + xx) : 0;
    const float* xp = xb + (size_t)a * CI;
#pragma unroll 2
    for (int cg = 0; cg < CI / 4; cg++) {
      float4 v = *(const float4*)(xp + cg * 4);
      float s0 = vld ? v.x : 0.f;
      float s1 = vld ? v.y : 0.f;
      float s2 = vld ? v.z : 0.f;
      float s3 = vld ? v.w : 0.f;
#pragma unroll
      for (int jg = 0; jg < 3; jg++) {
        const float* w0 = wP + (size_t)jg * CI * 72 + ((cg * 4) * 9 + t) * 8;
#pragma unroll
        for (int u = 0; u < 6; u++) {
          float a0 = fmaf(s0, w0[u], acc[jg * 6 + u]);
          float a1 = fmaf(s1, w0[72 + u], a0);
          float a2 = fmaf(s2, w0[144 + u], a1);
          acc[jg * 6 + u] = fmaf(s3, w0[216 + u], a2);
        }
      }
    }
  }
#pragma unroll
  for (int j = 0; j < 18; j++)
    off[((size_t)b * 18 + j) * HW + px] = acc[j];
}

// ---------------------------------------------------------------------------
// Deform conv (L1-L4), og-split per-pixel-thread (R10 form).
// ---------------------------------------------------------------------------
template<int CI, int CO, int OGC, int TPBK>
__global__ __launch_bounds__(TPBK) void dfc_og(
    const float* __restrict__ x, const float* __restrict__ off,
    const float* __restrict__ wP, float* __restrict__ out,
    int B, int H, int W) {
  constexpr int COG = CO / OGC;
  const int HW = H * W;
  const int npb = HW / TPBK;
  const int bid = xcd_swz(blockIdx.x, gridDim.x);
  const int og = bid % OGC;
  const int pxb = (bid / OGC) % npb;
  const int b = bid / (OGC * npb);
  const int px = pxb * TPBK + threadIdx.x;
  const int w = px % W, h = px / W;
  const float* xb = x + (size_t)b * HW * CI;   // NHWC

  float offv[18];
  const float* ob = off + (size_t)b * 18 * HW + px;
#pragma unroll
  for (int j = 0; j < 18; j++) offv[j] = ob[(size_t)j * HW];

  float acc[COG];
#pragma unroll
  for (int o = 0; o < COG; o++) acc[o] = 0.f;

#pragma unroll
  for (int k = 0; k < 9; k++) {
    float py = (float)(h - 1 + k / 3) + offv[2 * k];
    float pxx = (float)(w - 1 + k % 3) + offv[2 * k + 1];
    float fy = floorf(py), fx = floorf(pxx);
    float wy = py - fy, wx = pxx - fx;
    int y0 = (int)fy, x0 = (int)fx;
    int y1 = y0 + 1, x1 = x0 + 1;
    bool vy0 = (y0 >= 0) & (y0 < H), vy1 = (y1 >= 0) & (y1 < H);
    bool vx0 = (x0 >= 0) & (x0 < W), vx1 = (x1 >= 0) & (x1 < W);
    int yc0 = min(max(y0, 0), H - 1), yc1 = min(max(y1, 0), H - 1);
    int xc0 = min(max(x0, 0), W - 1), xc1 = min(max(x1, 0), W - 1);
    float w00 = (vy0 && vx0) ? (1.f - wy) * (1.f - wx) : 0.f;
    float w01 = (vy0 && vx1) ? (1.f - wy) * wx : 0.f;
    float w10 = (vy1 && vx0) ? wy * (1.f - wx) : 0.f;
    float w11 = (vy1 && vx1) ? wy * wx : 0.f;
    const float* p00 = xb + (size_t)(yc0 * W + xc0) * CI;
    const float* p01 = xb + (size_t)(yc0 * W + xc1) * CI;
    const float* p10 = xb + (size_t)(yc1 * W + xc0) * CI;
    const float* p11 = xb + (size_t)(yc1 * W + xc1) * CI;
#pragma unroll 2
    for (int cg = 0; cg < CI / 4; cg++) {
      float4 v00 = *(const float4*)(p00 + cg * 4);
      float4 v01 = *(const float4*)(p01 + cg * 4);
      float4 v10 = *(const float4*)(p10 + cg * 4);
      float4 v11 = *(const float4*)(p11 + cg * 4);
      float s0 = v00.x * w00 + v01.x * w01 + v10.x * w10 + v11.x * w11;
      float s1 = v00.y * w00 + v01.y * w01 + v10.y * w10 + v11.y * w11;
      float s2 = v00.z * w00 + v01.z * w01 + v10.z * w10 + v11.z * w11;
      float s3 = v00.w * w00 + v01.w * w01 + v10.w * w10 + v11.w * w11;
      const float* wr = wP + (size_t)(k * CI + cg * 4) * CO + og * COG;
#pragma unroll
      for (int o = 0; o < COG; o++) {
        float a0 = fmaf(s0, wr[o], acc[o]);
        float a1 = fmaf(s1, wr[CO + o], a0);
        float a2 = fmaf(s2, wr[2 * CO + o], a1);
        acc[o] = fmaf(s3, wr[3 * CO + o], a2);
      }
    }
  }

  float* op = out + ((size_t)b * CO + og * COG) * HW + px;
#pragma unroll
  for (int o = 0; o < COG; o++) op[(size_t)o * HW] = acc[o];
}

// ---------------------------------------------------------------------------
// BatchNorm (training stats, y NCHW) + LeakyReLU; apply writes NHWC or NCHW.
// ---------------------------------------------------------------------------
__global__ void bn_stats_kernel(const float* __restrict__ y,
                                double* __restrict__ st,
                                int B, int C, int HW, int NB) {
  int c = blockIdx.x / NB;
  int sl = blockIdx.x % NB;
  int tid = threadIdx.x;
  double s = 0.0, s2 = 0.0;
  int HW4 = HW >> 2;
  for (int b = 0; b < B; b++) {
    const float4* p = (const float4*)(y + ((size_t)b * C + c) * HW);
    for (int i = sl * TPB + tid; i < HW4; i += NB * TPB) {
      float4 v = p[i];
      s += (double)v.x + (double)v.y + (double)v.z + (double)v.w;
      s2 += (double)v.x * v.x + (double)v.y * v.y
          + (double)v.z * v.z + (double)v.w * v.w;
    }
  }
  __shared__ double rs[TPB], rq[TPB];
  rs[tid] = s;
  rq[tid] = s2;
  __syncthreads();
  for (int o = TPB / 2; o > 0; o >>= 1) {
    if (tid < o) { rs[tid] += rs[tid + o]; rq[tid] += rq[tid + o]; }
    __syncthreads();
  }
  if (tid == 0) {
    atomicAdd(&st[2 * c], rs[0]);
    atomicAdd(&st[2 * c + 1], rq[0]);
  }
}

__global__ void bn_finalize_kernel(const double* __restrict__ st,
                                   const float* __restrict__ g,
                                   const float* __restrict__ bb,
                                   float* __restrict__ ss, int C, int N) {
  int c = threadIdx.x;
  if (c >= C) return;
  double mean = st[2 * c] / N;
  double var = st[2 * c + 1] / N - mean * mean;
  float inv = (float)(1.0 / sqrt(var + 1e-5));
  float sc = g[c] * inv;
  ss[c] = sc;
  ss[C + c] = bb[c] - (float)mean * sc;
}

// NCHW -> NCHW (final output)
__global__ void bn_apply_kernel(const float* __restrict__ y,
                                const float* __restrict__ ss,
                                float* __restrict__ out, int C, int HW, int n) {
  int i = blockIdx.x * TPB + threadIdx.x;
  if (i >= n) return;
  int c = (i / HW) % C;
  float v = fmaf(y[i], ss[c], ss[C + c]);
  out[i] = v > 0.f ? v : 0.01f * v;
}

// NCHW -> NHWC (no pool; L3)
__global__ void bn_apply_nhwc_kernel(const float* __restrict__ y,
                                     const float* __restrict__ ss,
                                     float* __restrict__ out,
                                     int C, int H, int W, int n) {
  int i = blockIdx.x * TPB + threadIdx.x;
  if (i >= n) return;
  int c = i % C;
  int pix = i / C;
  int w = pix % W;
  int h = (pix / W) % H;
  int b = pix / (W * H);
  float v = fmaf(y[(((size_t)b * C + c) * H + h) * W + w], ss[c], ss[C + c]);
  out[i] = v > 0.f ? v : 0.01f * v;
}

// NCHW -> 2x2 maxpool -> NHWC (L0,L1,L2)
__global__ void bn_apply_pool_nhwc_kernel(const float* __restrict__ y,
                                          const float* __restrict__ ss,
                                          float* __restrict__ out,
                                          int C, int H, int W, int n) {
  int i = blockIdx.x * TPB + threadIdx.x;
  if (i >= n) return;
  int Wp = W >> 1, Hp = H >> 1;
  int c = i % C;
  int pw = (i / C) % Wp;
  int ph = (i / C / Wp) % Hp;
  int b = i / (C * Wp * Hp);
  const float* yp = y + (((size_t)b * C + c) * H + 2 * ph) * W + 2 * pw;
  float sc = ss[c], sh = ss[C + c];
  float v0 = fmaf(yp[0], sc, sh);     v0 = v0 > 0.f ? v0 : 0.01f * v0;
  float v1 = fmaf(yp[1], sc, sh);     v1 = v1 > 0.f ? v1 : 0.01f * v1;
  float v2 = fmaf(yp[W], sc, sh);     v2 = v2 > 0.f ? v2 : 0.01f * v2;
  float v3 = fmaf(yp[W + 1], sc, sh); v3 = v3 > 0.f ? v3 : 0.01f * v3;
  out[i] = fmaxf(fmaxf(v0, v1), fmaxf(v2, v3));
}

extern "C" void kernel_launch(void* const* d_in, const int* in_sizes, int n_in,
                              void* d_out, int out_size, void* d_ws, size_t ws_size,
                              hipStream_t stream) {
  const float* x = (const float*)d_in[0];
  const float *woff[5], *boff[5], *wm[5], *g[5], *bb[5];
  for (int i = 0; i < 5; i++) {
    woff[i] = (const float*)d_in[1 + 5 * i + 0];
    boff[i] = (const float*)d_in[1 + 5 * i + 1];
    wm[i]   = (const float*)d_in[1 + 5 * i + 2];
    g[i]    = (const float*)d_in[1 + 5 * i + 3];
    bb[i]   = (const float*)d_in[1 + 5 * i + 4];
  }

  const size_t need =
      (size_t)(16777216 + 4718592 + 4194304 + 2097152 + PACK_FLOATS) * 4 + 6400 + 640;
  if (ws_size < need) return;

  float* conv_buf = (float*)d_ws;          // NCHW conv outputs (up to 67 MB)
  float* off_buf = conv_buf + 16777216;    // offsets [b][18][HW]
  float* xa = off_buf + 4718592;           // x1 / x3 (NHWC)
  float* xb2 = xa + 4194304;               // x2 / x4 (NHWC)
  float* wpk = xb2 + 2097152;              // packed weights
  double* st = (double*)(wpk + PACK_FLOATS);   // 5 x 160 doubles
  float* ss = (float*)(st + 800);

  const int B = 8;

  {
    PackSrc psrc;
    for (int i = 0; i < 5; i++) { psrc.p[i] = wm[i]; psrc.p[5 + i] = woff[i]; }
    pack_weights<<<dim3(180, 10), TPB, 0, stream>>>(psrc, wpk);
    hipMemsetAsync(st, 0, 800 * sizeof(double), stream);   // all layers' stats
  }

  // ---- Layer 0: CI=1, CO=16, 128x1024, fused offsets, pool -> xa (NHWC)
  {
    const int H = 128, W = 1024;
    dfc_fused0<<<B * H * W / TPB, TPB, 0, stream>>>(
        x, wpk + OWO0, boff[0], wpk + OWM0, conv_buf, B, H, W);
    bn_stats_kernel<<<16 * 32, TPB, 0, stream>>>(conv_buf, st, B, 16, H * W, 32);
    bn_finalize_kernel<<<1, TPB, 0, stream>>>(st, g[0], bb[0], ss, 16, B * H * W);
    int n = B * 16 * (H / 2) * (W / 2);
    bn_apply_pool_nhwc_kernel<<<n / TPB, TPB, 0, stream>>>(
        conv_buf, ss, xa, 16, H, W, n);
  }
  // ---- Layer 1: CI=16, CO=32, 64x512, pool -> xb2 (NHWC), off18 + OGC=1
  {
    const int H = 64, W = 512;
    off_conv18<16, 256><<<B * (H * W / 256), 256, 0, stream>>>(
        xa, wpk + OWO1, boff[1], off_buf, B, H, W);
    dfc_og<16, 32, 1, 256><<<B * (H * W / 256), 256, 0, stream>>>(
        xa, off_buf, wpk + OWM1, conv_buf, B, H, W);
    bn_stats_kernel<<<32 * 32, TPB, 0, stream>>>(conv_buf, st + 160, B, 32, H * W, 32);
    bn_finalize_kernel<<<1, TPB, 0, stream>>>(st + 160, g[1], bb[1], ss, 32, B * H * W);
    int n = B * 32 * (H / 2) * (W / 2);
    bn_apply_pool_nhwc_kernel<<<n / TPB, TPB, 0, stream>>>(
        conv_buf, ss, xb2, 32, H, W, n);
  }
  // ---- Layer 2: CI=32, CO=48, 32x256, pool -> xa (NHWC), off18 + OGC=2
  {
    const int H = 32, W = 256;
    off_conv18<32, 256><<<B * (H * W / 256), 256, 0, stream>>>(
        xb2, wpk + OWO2, boff[2], off_buf, B, H, W);
    dfc_og<32, 48, 2, 256><<<B * (H * W / 256) * 2, 256, 0, stream>>>(
        xb2, off_buf, wpk + OWM2, conv_buf, B, H, W);
    bn_stats_kernel<<<48 * 16, TPB, 0, stream>>>(conv_buf, st + 320, B, 48, H * W, 16);
    bn_finalize_kernel<<<1, TPB, 0, stream>>>(st + 320, g[2], bb[2], ss, 48, B * H * W);
    int n = B * 48 * (H / 2) * (W / 2);
    bn_apply_pool_nhwc_kernel<<<n / TPB, TPB, 0, stream>>>(
        conv_buf, ss, xa, 48, H, W, n);
  }
  // ---- Layer 3: CI=48, CO=64, 16x128, no pool -> xb2 (NHWC), OGC=4
  {
    const int H = 16, W = 128;
    off_conv<48, 64><<<B * 3 * (H * W / 64), 64, 0, stream>>>(
        xa, wpk + OWO3, boff[3], off_buf, B, H, W);
    dfc_og<48, 64, 4, 64><<<B * (H * W / 64) * 4, 64, 0, stream>>>(
        xa, off_buf, wpk + OWM3, conv_buf, B, H, W);
    bn_stats_kernel<<<64 * 8, TPB, 0, stream>>>(conv_buf, st + 480, B, 64, H * W, 8);
    bn_finalize_kernel<<<1, TPB, 0, stream>>>(st + 480, g[3], bb[3], ss, 64, B * H * W);
    int n = B * 64 * H * W;
    bn_apply_nhwc_kernel<<<n / TPB, TPB, 0, stream>>>(
        conv_buf, ss, xb2, 64, H, W, n);
  }
  // ---- Layer 4: CI=64, CO=80, 16x128, no pool -> d_out (NCHW), OGC=5
  {
    const int H = 16, W = 128;
    off_conv<64, 64><<<B * 3 * (H * W / 64), 64, 0, stream>>>(
        xb2, wpk + OWO4, boff[4], off_buf, B, H, W);
    dfc_og<64, 80, 5, 64><<<B * (H * W / 64) * 5, 64, 0, stream>>>(
        xb2, off_buf, wpk + OWM4, conv_buf, B, H, W);
    bn_stats_kernel<<<80 * 8, TPB, 0, stream>>>(conv_buf, st + 640, B, 80, H * W, 8);
    bn_finalize_kernel<<<1, TPB, 0, stream>>>(st + 640, g[4], bb[4], ss, 80, B * H * W);
    int n = B * 80 * H * W;
    bn_apply_kernel<<<n / TPB, TPB, 0, stream>>>(
        conv_buf, ss, (float*)d_out, 80, H * W, n);
  }
}